// Round 3
// baseline (306.607 us; speedup 1.0000x reference)
//
#include <hip/hip_runtime.h>
#include <cstdint>
#include <cstddef>

typedef __bf16 bf16x8 __attribute__((ext_vector_type(8)));
typedef __bf16 bf16x4 __attribute__((ext_vector_type(4)));
typedef float  f32x4  __attribute__((ext_vector_type(4)));

#define MFMA16(a, b, c) __builtin_amdgcn_mfma_f32_16x16x32_bf16((a), (b), (c), 0, 0, 0)

// async global->LDS, 16B per lane. LDS dest MUST be wave_base + lane*16 (contiguous).
#define GLL16(gsrc, ldst)                                                              \
  __builtin_amdgcn_global_load_lds((__attribute__((address_space(1))) void*)(gsrc),    \
                                   (__attribute__((address_space(3))) void*)(ldst),    \
                                   16, 0, 0)

// q pre-scale: 1/sqrt(64) * log2(e), so attention scores land in log2 space
#define QSCALE 0.1803368801111204f

// ---------------------------------------------------------------- conversions

__global__ __launch_bounds__(256)
void cvt_f32_bf16(const float* __restrict__ in, __bf16* __restrict__ out, int n4)
{
    int i = blockIdx.x * 256 + threadIdx.x;
    if (i < n4) {
        float4 v = ((const float4*)in)[i];
        bf16x4 o;
        o[0] = (__bf16)v.x; o[1] = (__bf16)v.y; o[2] = (__bf16)v.z; o[3] = (__bf16)v.w;
        ((bf16x4*)out)[i] = o;
    }
}

// in: fp32 [K][N] row-major -> out: bf16 [N][K] row-major
__global__ __launch_bounds__(256)
void transpose_cvt(const float* __restrict__ in, __bf16* __restrict__ out, int K, int N)
{
    __shared__ __bf16 tile[32][33];
    const int n0 = blockIdx.x * 32, k0 = blockIdx.y * 32;
    const int tx = threadIdx.x, ty = threadIdx.y;
    #pragma unroll
    for (int i = 0; i < 4; ++i)
        tile[ty + i * 8][tx] = (__bf16)in[(size_t)(k0 + ty + i * 8) * N + n0 + tx];
    __syncthreads();
    #pragma unroll
    for (int i = 0; i < 4; ++i)
        out[(size_t)(n0 + ty + i * 8) * K + k0 + tx] = tile[tx][ty + i * 8];
}

// ---------------------------------------------------------------- v transpose
// vout fp32 [bh][t][64] -> vwst bf16 [bh][64][2048], with the sigma column
// permutation within each 64-block of t: position p holds t = 16*(p&3)+(p>>2),
// matching the packed P-store order (c_store = 4*lr + ni) in attn_fused.

__global__ __launch_bounds__(256)
void vtrans(const float* __restrict__ vout, __bf16* __restrict__ vwst)
{
    const int bh = blockIdx.y;
    const int t0 = blockIdx.x * 64;
    const int tid = threadIdx.x;

    __shared__ __bf16 VT[64][68];   // [d][p]

    const int tr = tid >> 4;        // t sub-row 0..15
    const int dc = (tid & 15) * 4;  // d col 0..60

    float4 vals[4];
    #pragma unroll
    for (int i = 0; i < 4; ++i)
        vals[i] = *(const float4*)&vout[((size_t)bh * 2048 + t0 + tr + 16 * i) * 64 + dc];

    // p(t_local = tr + 16*i) = 4*tr + i  -> the 4 i-values are consecutive in p
    #pragma unroll
    for (int j = 0; j < 4; ++j) {
        bf16x4 pk;
        pk[0] = (__bf16)(&vals[0].x)[j];
        pk[1] = (__bf16)(&vals[1].x)[j];
        pk[2] = (__bf16)(&vals[2].x)[j];
        pk[3] = (__bf16)(&vals[3].x)[j];
        *(bf16x4*)&VT[dc + j][4 * tr] = pk;
    }
    __syncthreads();

    #pragma unroll
    for (int k = 0; k < 2; ++k) {
        const int c = tid + 256 * k;
        const int d = c >> 3, off = (c & 7) * 8;
        bf16x8 v = *(const bf16x8*)&VT[d][off];
        *(bf16x8*)&vwst[((size_t)bh * 64 + d) * 2048 + t0 + off] = v;
    }
}

// ---------------------------------------------------------------- QKV GEMM
// 256x192 tile, BK=64 (two 32-col panels), 512 threads = 8 waves (2M x 4N).
// Grid 16x32 = 512 blocks = exactly 2 rounds of 256 CUs (1 block/CU, 112 KB LDS).
//
// Schedule v2: software-pipelined fragment reads (frags for phase p+1 are
// ds_read between phase p's MFMA issue, so LDS and MFMA pipes co-issue within
// each barrier-delimited region even though the asm barriers are compiler
// fences), and barriers reduced 16 -> 6 per iteration (kept only where a
// RAW/WAR hazard requires one):
//   (f)->.. stage1 | R1 lda+12MFMA | R2 lda/ldb+12MFMA | (a) stage3 |
//   R3 lda+12MFMA | wait vmcnt(2) (b) | R4 lda/ldb+12MFMA | (c) stage5 |
//   R5 lda+12MFMA | R6 lda/ldb+12MFMA | (d) stage7 | R7 lda+12MFMA |
//   wait vmcnt(2) (e) | R8 lda/ldb+12MFMA | (f)
// RAW: every pipelined read's source panel is drained by the preceding vmcnt
// wait + barrier. WAR: every stage-group's target panel had its last consumer
// MFMA retire a barrier earlier ((a) for stage3, (c) for stage5, (d) for
// stage7, (f) for stage1). vmcnt counts: steady in-flight pattern
// [2]+5->[7]+2->[9] -w2-> [2]+5->[7]+2->[9] -w2-> [2].

__global__ __launch_bounds__(512, 2)
void gemm_qkv(const __bf16* __restrict__ A, const __bf16* __restrict__ Bt,
              const float* __restrict__ bias,
              __bf16* __restrict__ qws, float* __restrict__ kout, float* __restrict__ vout,
              __bf16* __restrict__ kws)
{
    constexpr int K = 1024;
    const int m0 = blockIdx.y * 256, n0 = blockIdx.x * 192;
    const int tid = threadIdx.x;
    const int wave = tid >> 6, lane = tid & 63;
    const int quad = lane >> 4, lr = lane & 15;
    const int wrow = (wave & 1) * 128, wcol = (wave >> 1) * 48;

    __shared__ __bf16 As[2][2][256][32];   // [buf][kc][row][col'] 64 KB
    __shared__ __bf16 Bs[2][2][192][32];   // [buf][kc][row][col'] 48 KB

    f32x4 acc[8][3];
    #pragma unroll
    for (int mi = 0; mi < 8; ++mi)
      #pragma unroll
      for (int ni = 0; ni < 3; ++ni)
        #pragma unroll
        for (int c = 0; c < 4; ++c) acc[mi][ni][c] = 0.f;

    // ---- stage address setup (pre-swizzled global source, linear LDS dest)
    const __bf16* gA[4];
    #pragma unroll
    for (int l = 0; l < 4; ++l) {
        const int u = tid + 512 * l;            // 0..2047
        const int kc = u >> 10;                 // loads 0,1 -> kc0; 2,3 -> kc1
        const int row = (u >> 2) & 255;
        const int cg = ((u & 3) ^ ((u >> 3) & 3)) * 8;
        gA[l] = A + (size_t)(m0 + row) * K + kc * 32 + cg;
    }
    const __bf16* gB[3];
    #pragma unroll
    for (int l = 0; l < 3; ++l) {
        const int u = tid + 512 * l;            // 0..1535
        const int kc = (u >= 768);
        const int row = (u - kc * 768) >> 2;
        const int cg = ((u & 3) ^ ((u >> 3) & 3)) * 8;
        gB[l] = Bt + (size_t)(n0 + row) * K + kc * 32 + cg;
    }
    char* lA = (char*)As + tid * 16;   // + l*8192 per load slot, + buf*32768
    char* lB = (char*)Bs + tid * 16;   // + l*8192 per load slot, + buf*24576

    const int sw = (quad ^ ((lr >> 1) & 3)) * 8;

#define BARF  asm volatile("s_barrier" ::: "memory")
#define WAITV2 asm volatile("s_waitcnt vmcnt(2)" ::: "memory")
#define WAITV0 asm volatile("s_waitcnt vmcnt(0)" ::: "memory")

#define LDB(bf, buf, kc)                                                   \
    do {                                                                   \
        bf[0] = *(const bf16x8*)&Bs[buf][kc][wcol      + lr][sw];          \
        bf[1] = *(const bf16x8*)&Bs[buf][kc][wcol + 16 + lr][sw];          \
        bf[2] = *(const bf16x8*)&Bs[buf][kc][wcol + 32 + lr][sw];          \
    } while (0)

#define LDA(af, buf, kc, mh)                                                  \
    do {                                                                      \
        af[0] = *(const bf16x8*)&As[buf][kc][wrow + (mh)*64      + lr][sw];   \
        af[1] = *(const bf16x8*)&As[buf][kc][wrow + (mh)*64 + 16 + lr][sw];   \
        af[2] = *(const bf16x8*)&As[buf][kc][wrow + (mh)*64 + 32 + lr][sw];   \
        af[3] = *(const bf16x8*)&As[buf][kc][wrow + (mh)*64 + 48 + lr][sw];   \
    } while (0)

#define FMA12(af, bf, mh)                                                  \
    do {                                                                   \
        __builtin_amdgcn_s_setprio(1);                                     \
        acc[(mh)*4+0][0] = MFMA16(af[0], bf[0], acc[(mh)*4+0][0]);         \
        acc[(mh)*4+0][1] = MFMA16(af[0], bf[1], acc[(mh)*4+0][1]);         \
        acc[(mh)*4+0][2] = MFMA16(af[0], bf[2], acc[(mh)*4+0][2]);         \
        acc[(mh)*4+1][0] = MFMA16(af[1], bf[0], acc[(mh)*4+1][0]);         \
        acc[(mh)*4+1][1] = MFMA16(af[1], bf[1], acc[(mh)*4+1][1]);         \
        acc[(mh)*4+1][2] = MFMA16(af[1], bf[2], acc[(mh)*4+1][2]);         \
        acc[(mh)*4+2][0] = MFMA16(af[2], bf[0], acc[(mh)*4+2][0]);         \
        acc[(mh)*4+2][1] = MFMA16(af[2], bf[1], acc[(mh)*4+2][1]);         \
        acc[(mh)*4+2][2] = MFMA16(af[2], bf[2], acc[(mh)*4+2][2]);         \
        acc[(mh)*4+3][0] = MFMA16(af[3], bf[0], acc[(mh)*4+3][0]);         \
        acc[(mh)*4+3][1] = MFMA16(af[3], bf[1], acc[(mh)*4+3][1]);         \
        acc[(mh)*4+3][2] = MFMA16(af[3], bf[2], acc[(mh)*4+3][2]);         \
        __builtin_amdgcn_s_setprio(0);                                     \
    } while (0)

    // ---- prologue: tile0 -> buf0 (7 loads), A-kc0(tile1) -> buf1 (2 loads)
    GLL16(gA[0], lA);
    GLL16(gA[1], lA + 8192);
    GLL16(gA[2], lA + 16384);
    GLL16(gA[3], lA + 24576);
    GLL16(gB[0], lB);
    GLL16(gB[1], lB + 8192);
    GLL16(gB[2], lB + 16384);
    GLL16(gA[0] + 64, lA + 32768);
    GLL16(gA[1] + 64, lA + 40960);
    WAITV2;
    BARF;

    bf16x8 afA[4], afB[4], bfA[3], bfB[3];
    LDB(bfA, 0, 0);
    LDA(afA, 0, 0, 0);

    for (int it = 0; it < 8; ++it) {
        const bool more = (it < 7);

        // R1: stage buf1 tail (A-kc1(T+1) + B(T+1)); compute (buf0,kc0,mh0)
        GLL16(gA[2] + 64, lA + 49152);
        GLL16(gA[3] + 64, lA + 57344);
        GLL16(gB[0] + 64, lB + 24576);
        GLL16(gB[1] + 64, lB + 32768);
        GLL16(gB[2] + 64, lB + 40960);
        LDA(afB, 0, 0, 1);
        FMA12(afA, bfA, 0);

        // R2: compute (buf0,kc0,mh1)
        LDA(afA, 0, 1, 0);
        LDB(bfB, 0, 1);
        FMA12(afB, bfA, 1);
        BARF;                                   // (a) protects stage3 WAR

        // R3: stage buf0 A-kc0(T+2); compute (buf0,kc1,mh0)
        if (more) { GLL16(gA[0] + 128, lA); GLL16(gA[1] + 128, lA + 8192); }
        LDA(afB, 0, 1, 1);
        FMA12(afA, bfB, 0);

        // R4: drain tile T+1 (prev ph7's 2 + ph1's 5); compute (buf0,kc1,mh1)
        if (more) WAITV2; else WAITV0;
        BARF;                                   // (b) publishes tile T+1
        LDA(afA, 1, 0, 0);
        LDB(bfA, 1, 0);
        FMA12(afB, bfB, 1);
        BARF;                                   // (c) protects stage5 WAR

        // R5: stage buf0 tail (A-kc1(T+2) + B(T+2)); compute (buf1,kc0,mh0)
        if (more) {
            GLL16(gA[2] + 128, lA + 16384);
            GLL16(gA[3] + 128, lA + 24576);
            GLL16(gB[0] + 128, lB);
            GLL16(gB[1] + 128, lB + 8192);
            GLL16(gB[2] + 128, lB + 16384);
        }
        LDA(afB, 1, 0, 1);
        FMA12(afA, bfA, 0);

        // R6: compute (buf1,kc0,mh1)
        LDA(afA, 1, 1, 0);
        LDB(bfB, 1, 1);
        FMA12(afB, bfA, 1);
        BARF;                                   // (d) protects stage7 WAR

        // R7: stage buf1 A-kc0(T+3); compute (buf1,kc1,mh0)
        if (more) { GLL16(gA[0] + 192, lA + 32768); GLL16(gA[1] + 192, lA + 40960); }
        LDA(afB, 1, 1, 1);
        FMA12(afA, bfB, 0);

        // R8: drain tile T+2 (ph3's 2 + ph5's 5); compute (buf1,kc1,mh1)
        if (more) WAITV2; else WAITV0;
        BARF;                                   // (e) publishes tile T+2
        LDA(afA, 0, 0, 0);
        LDB(bfA, 0, 0);
        FMA12(afB, bfB, 1);
        BARF;                                   // (f) protects stage1 WAR

        #pragma unroll
        for (int l = 0; l < 4; ++l) gA[l] += 128;
        #pragma unroll
        for (int l = 0; l < 3; ++l) gB[l] += 128;
    }

#undef FMA12
#undef LDA
#undef LDB
#undef BARF
#undef WAITV2
#undef WAITV0

    // ---- epilogue (sec per-frag: 192-tile can straddle the 1024 section boundary)
    #pragma unroll
    for (int ni = 0; ni < 3; ++ni) {
        const int gn = n0 + wcol + ni * 16 + lr;
        const float bv = bias[gn];
        const int sec = gn >> 10;  // uniform within frag (base 16-aligned)
        const int cn = gn & 1023, hh = cn >> 6, dd = cn & 63;
        #pragma unroll
        for (int mi = 0; mi < 8; ++mi) {
            const int gm0 = m0 + wrow + mi * 16 + quad * 4;
            const int b = gm0 >> 11, t0 = gm0 & 2047;
            const size_t tb = ((size_t)b * 16 + hh) * 2048;
            if (sec == 0) {
                #pragma unroll
                for (int r = 0; r < 4; ++r)
                    qws[(tb + t0 + r) * 64 + dd] = (__bf16)((acc[mi][ni][r] + bv) * QSCALE);
            } else if (sec == 1) {
                #pragma unroll
                for (int r = 0; r < 4; ++r) {
                    const float val = acc[mi][ni][r] + bv;
                    kout[(tb + t0 + r) * 64 + dd] = val;
                    kws [(tb + t0 + r) * 64 + dd] = (__bf16)val;
                }
            } else {
                #pragma unroll
                for (int r = 0; r < 4; ++r)
                    vout[(tb + t0 + r) * 64 + dd] = acc[mi][ni][r] + bv;
            }
        }
    }
}

// ---------------------------------------------------------------- out-proj GEMM
// 64x128 tile, grid (8,128) = 1024 blocks -> 4 blocks/CU for latency hiding.

__global__ __launch_bounds__(256)
void gemm_out(const __bf16* __restrict__ A, const __bf16* __restrict__ Bt,
              const float* __restrict__ bias, float* __restrict__ y)
{
    constexpr int K = 1024;
    const int m0 = blockIdx.y * 64, n0 = blockIdx.x * 128;
    const int tid = threadIdx.x;
    const int wave = tid >> 6, lane = tid & 63;
    const int quad = lane >> 4, lr = lane & 15;
    const int wrow = (wave & 1) * 32, wcol = (wave >> 1) * 64;

    __shared__ __bf16 As[64 * 32];
    __shared__ __bf16 Bs[128 * 32];

    f32x4 acc[2][4];
    #pragma unroll
    for (int mi = 0; mi < 2; ++mi)
      #pragma unroll
      for (int ni = 0; ni < 4; ++ni)
        #pragma unroll
        for (int c = 0; c < 4; ++c) acc[mi][ni][c] = 0.f;

    const int ua = tid, u0 = tid, u1 = tid + 256;
    const int cga = ((ua & 3) ^ ((ua >> 3) & 3)) * 8;
    const int cg0 = ((u0 & 3) ^ ((u0 >> 3) & 3)) * 8;
    const int cg1 = ((u1 & 3) ^ ((u1 >> 3) & 3)) * 8;
    const __bf16* ga  = A  + (size_t)(m0 + (ua >> 2)) * K + cga;
    const __bf16* gb0 = Bt + (size_t)(n0 + (u0 >> 2)) * K + cg0;
    const __bf16* gb1 = Bt + (size_t)(n0 + (u1 >> 2)) * K + cg1;
    __bf16* la  = As + ua * 8;
    __bf16* lb0 = Bs + u0 * 8;
    __bf16* lb1 = Bs + u1 * 8;

    const int sw = (quad ^ ((lr >> 1) & 3)) * 8;

    for (int kt = 0; kt < K; kt += 32) {
        __syncthreads();
        GLL16(ga + kt, la);
        GLL16(gb0 + kt, lb0);
        GLL16(gb1 + kt, lb1);
        __syncthreads();
        bf16x8 af[2], bfv[4];
        #pragma unroll
        for (int mi = 0; mi < 2; ++mi)
            af[mi] = *(const bf16x8*)&As[(wrow + mi * 16 + lr) * 32 + sw];
        #pragma unroll
        for (int ni = 0; ni < 4; ++ni)
            bfv[ni] = *(const bf16x8*)&Bs[(wcol + ni * 16 + lr) * 32 + sw];
        #pragma unroll
        for (int mi = 0; mi < 2; ++mi)
          #pragma unroll
          for (int ni = 0; ni < 4; ++ni)
            acc[mi][ni] = MFMA16(af[mi], bfv[ni], acc[mi][ni]);
    }

    #pragma unroll
    for (int ni = 0; ni < 4; ++ni) {
        const int gn = n0 + wcol + ni * 16 + lr;
        const float bv = bias[gn];
        #pragma unroll
        for (int mi = 0; mi < 2; ++mi) {
            #pragma unroll
            for (int r = 0; r < 4; ++r) {
                const int gm = m0 + wrow + mi * 16 + quad * 4 + r;
                y[(size_t)gm * 1024 + gn] = acc[mi][ni][r] + bv;
            }
        }
    }
}

// ---------------------------------------------------------------- flash attention
// Grid (bh, pair): all 8 pair-blocks of a bh land on one XCD (linear id % 8 = bh % 8).
// Two serialized phases (q-tiles {x,15-x}), 34 tile-iters per block. Fixed-shift
// softmax: sacc init = -12, p = exp2(s-12), exact after final 1/l (no running max).
// 3-buffer KV, 2-deep prefetch, ONE barrier per iter (prefetch targets buf+2).

__global__ __launch_bounds__(256, 2)
void attn_fused(const __bf16* __restrict__ qws, const __bf16* __restrict__ kws,
                const __bf16* __restrict__ vwst, __bf16* __restrict__ attnws)
{
    const int bh = blockIdx.x;          // b*16 + h
    const int tid = threadIdx.x;
    const int wave = tid >> 6, lane = tid & 63;
    const int quad = lane >> 4, lr = lane & 15;

    const int jqp[2] = { (int)blockIdx.y, 15 - (int)blockIdx.y };
    const int ntp[2] = { 2 * (jqp[0] + 1), 2 * (jqp[1] + 1) };
    const int nt0 = ntp[0];
    const int ntot = 34;

    __shared__ __bf16 Ks [3][2][64][32];   // [buf][s][kv][d32]   swizzled cols
    __shared__ __bf16 Vts[3][2][64][32];   // [buf][s][d][p32]    swizzled cols
    __shared__ __bf16 Ps [4][32][72];      // per-wave P, c_store = 4*lr+ni order

    // staging addresses
    const int srow = tid >> 2;
    const int scg  = ((tid & 3) ^ ((tid >> 3) & 3)) * 8;
    const __bf16* kb = kws  + ((size_t)bh * 2048 + srow) * 64 + scg;
    const __bf16* vb = vwst + ((size_t)bh * 64 + srow) * 2048 + scg;
    char* lk = (char*)Ks  + tid * 16;   // + buf*8192 (+4096 for s1)
    char* lv = (char*)Vts + tid * 16;

    const int sw = (quad ^ ((lr >> 1) & 3)) * 8;

    bf16x8 ones;
    #pragma unroll
    for (int j = 0; j < 8; ++j) ones[j] = (__bf16)1.0f;

    // Q fragments for BOTH phases up-front (keeps vmcnt FIFO discipline clean)
    bf16x8 aq[2][2][2];
    #pragma unroll
    for (int h = 0; h < 2; ++h)
      #pragma unroll
      for (int mi = 0; mi < 2; ++mi) {
        const __bf16* qb = qws + ((size_t)bh * 2048 + jqp[h] * 128 + wave * 32 + mi * 16 + lr) * 64 + quad * 8;
        aq[h][mi][0] = *(const bf16x8*)qb;
        aq[h][mi][1] = *(const bf16x8*)(qb + 32);
      }

#define PREFETCH(j, buf)                                                \
    do {                                                                \
        GLL16(kb + (size_t)(j) * 4096,      lk + (buf) * 8192);         \
        GLL16(kb + (size_t)(j) * 4096 + 32, lk + (buf) * 8192 + 4096);  \
        GLL16(vb + (j) * 64,                lv + (buf) * 8192);         \
        GLL16(vb + (j) * 64 + 32,           lv + (buf) * 8192 + 4096);  \
    } while (0)

    // prologue: tiles 0 and 1 (phase-0 always has >= 2 tiles)
    PREFETCH(0, 0);
    PREFETCH(1, 1);

    bf16x4 oreg[2][2][4];   // [h][mi][n], r packed in vector lanes

    int pos = 0;
    for (int h = 0; h < 2; ++h) {
        const int jq = jqp[h];
        const int NT = ntp[h];

        f32x4 o_acc[2][4], l_acc[2];
        #pragma unroll
        for (int mi = 0; mi < 2; ++mi) {
            #pragma unroll
            for (int r = 0; r < 4; ++r) l_acc[mi][r] = 0.f;
            #pragma unroll
            for (int n = 0; n < 4; ++n)
                #pragma unroll
                for (int r = 0; r < 4; ++r) o_acc[mi][n][r] = 0.f;
        }

        for (int jt = 0; jt < NT; ++jt, ++pos) {
            const int cur = pos % 3;
            // tile `pos` was requested 2 iters ago; tile pos+1 is 1 deep in flight
            if (pos + 1 < ntot) {
                asm volatile("s_waitcnt vmcnt(4)" ::: "memory");
            } else {
                asm volatile("s_waitcnt vmcnt(0)" ::: "memory");
            }
            asm volatile("s_waitcnt lgkmcnt(0)" ::: "memory");
            asm volatile("s_barrier" ::: "memory");
            if (pos + 2 < ntot) {
                const int p2 = pos + 2;
                const int nj = (p2 < nt0) ? p2 : p2 - nt0;
                PREFETCH(nj, p2 % 3);
            }

            const bool lastTile = (jt == NT - 1);
            if (!(lastTile && wave < 2)) {
                // S = Q K^T, C initialized to -12 (fixed softmax shift, free)
                bf16x8 bk[4][2];
                #pragma unroll
                for (int ni = 0; ni < 4; ++ni) {
                    bk[ni][0] = *(const bf16x8*)&Ks[cur][0][ni * 16 + lr][sw];
                    bk[ni][1] = *(const bf16x8*)&Ks[cur][1][ni * 16 + lr][sw];
                }
                f32x4 sacc[2][4];
                #pragma unroll
                for (int mi = 0; mi < 2; ++mi)
                  #pragma unroll
                  for (int ni = 0; ni < 4; ++ni)
                    #pragma unroll
                    for (int c = 0; c < 4; ++c) sacc[mi][ni][c] = -12.f;
                #pragma unroll
                for (int ni = 0; ni < 4; ++ni)
                  #pragma unroll
                  for (int mi = 0; mi < 2; ++mi) {
                    sacc[mi][ni] = MFMA16(aq[h][mi][0], bk[ni][0], sacc[mi][ni]);
                    sacc[mi][ni] = MFMA16(aq[h][mi][1], bk[ni][1], sacc[mi][ni]);
                  }

                // causal mask: only waves whose rows straddle this tile
                const bool needMask = (jt == NT - 2 && wave < 2) || (lastTile && wave >= 2);
                if (needMask) {
                    const int c0 = jt * 64 + lr;
                    #pragma unroll
                    for (int mi = 0; mi < 2; ++mi) {
                        const int t0 = jq * 128 + wave * 32 + mi * 16 + quad * 4;
                        #pragma unroll
                        for (int ni = 0; ni < 4; ++ni)
                          #pragma unroll
                          for (int r = 0; r < 4; ++r)
                            if (c0 + ni * 16 > t0 + r) sacc[mi][ni][r] = -1e30f;
                    }
                }

                // p = exp2(s - 12); packed b64 store (no max, no alpha)
                #pragma unroll
                for (int mi = 0; mi < 2; ++mi)
                  #pragma unroll
                  for (int r = 0; r < 4; ++r) {
                    bf16x4 pp;
                    #pragma unroll
                    for (int ni = 0; ni < 4; ++ni)
                        pp[ni] = (__bf16)__builtin_amdgcn_exp2f(sacc[mi][ni][r]);
                    *(bf16x4*)&Ps[wave][mi * 16 + quad * 4 + r][4 * lr] = pp;
                  }

                // Ps is wave-private: drain own LDS writes, no barrier
                asm volatile("s_waitcnt lgkmcnt(0)" ::: "memory");

                // O += P V ; l += P . 1   (V rows sigma-permuted to match P)
                bf16x8 bv[4][2];
                #pragma unroll
                for (int n = 0; n < 4; ++n) {
                    bv[n][0] = *(const bf16x8*)&Vts[cur][0][n * 16 + lr][sw];
                    bv[n][1] = *(const bf16x8*)&Vts[cur][1][n * 16 + lr][sw];
                }
                #pragma unroll
                for (int mi = 0; mi < 2; ++mi) {
                    bf16x8 ap0 = *(const bf16x8*)&Ps[wave][mi * 16 + lr][quad * 8];
                    bf16x8 ap1 = *(const bf16x8*)&Ps[wave][mi * 16 + lr][32 + quad * 8];
                    l_acc[mi] = MFMA16(ap0, ones, l_acc[mi]);
                    l_acc[mi] = MFMA16(ap1, ones, l_acc[mi]);
                    #pragma unroll
                    for (int n = 0; n < 4; ++n) {
                        o_acc[mi][n] = MFMA16(ap0, bv[n][0], o_acc[mi][n]);
                        o_acc[mi][n] = MFMA16(ap1, bv[n][1], o_acc[mi][n]);
                    }
                }
            }
        }

        // normalize into registers (stores deferred to kernel end)
        #pragma unroll
        for (int mi = 0; mi < 2; ++mi)
          #pragma unroll
          for (int r = 0; r < 4; ++r) {
            const float inv = 1.f / l_acc[mi][r];
            #pragma unroll
            for (int n = 0; n < 4; ++n)
                oreg[h][mi][n][r] = (__bf16)(o_acc[mi][n][r] * inv);
          }
    }

    // epilogue: store both phases (bf16, [B,T,NH*HD] for the out-proj GEMM)
    const int b = bh >> 4, h16 = bh & 15;
    #pragma unroll
    for (int h = 0; h < 2; ++h)
      #pragma unroll
      for (int mi = 0; mi < 2; ++mi)
        #pragma unroll
        for (int r = 0; r < 4; ++r) {
            const int t = jqp[h] * 128 + wave * 32 + mi * 16 + quad * 4 + r;
            #pragma unroll
            for (int n = 0; n < 4; ++n)
                attnws[(((size_t)b * 2048 + t) * 16 + h16) * 64 + n * 16 + lr] =
                    oreg[h][mi][n][r];
        }
#undef PREFETCH
}

// ---------------------------------------------------------------- launcher

extern "C" void kernel_launch(void* const* d_in, const int* in_sizes, int n_in,
                              void* d_out, int out_size, void* d_ws, size_t ws_size,
                              hipStream_t stream)
{
    (void)in_sizes; (void)n_in; (void)out_size; (void)ws_size;

    const float* x    = (const float*)d_in[0];
    const float* Wqkv = (const float*)d_in[1];
    const float* bqkv = (const float*)d_in[2];
    const float* Wout = (const float*)d_in[3];
    const float* bout = (const float*)d_in[4];

    float* y    = (float*)d_out;          // [4,2048,1024]
    float* kout = y + 8388608;            // [4,16,2048,64]
    float* vout = kout + 8388608;         // [4,16,2048,64]

    char* ws = (char*)d_ws;
    __bf16* xb    = (__bf16*)(ws);                       // 16 MB  [8192,1024]
    __bf16* wqkvt = (__bf16*)(ws + (16u << 20));         //  6 MB  [3072,1024]
    __bf16* woutt = (__bf16*)(ws + (22u << 20));         //  2 MB  [1024,1024]
    __bf16* qws   = (__bf16*)(ws + (24u << 20));         // 16 MB  [64,2048,64]  (pre-scaled)
    __bf16* kws   = (__bf16*)(ws + (40u << 20));         // 16 MB  [64,2048,64]
    __bf16* vwst  = (__bf16*)(ws + (56u << 20));         // 16 MB  [64,64,2048]  (sigma-permuted)
    __bf16* attnw = (__bf16*)(ws + (72u << 20));         // 16 MB  [8192,1024]

    cvt_f32_bf16<<<8192, 256, 0, stream>>>(x, xb, 2097152);
    transpose_cvt<<<dim3(96, 32), dim3(32, 8), 0, stream>>>(Wqkv, wqkvt, 1024, 3072);
    transpose_cvt<<<dim3(32, 32), dim3(32, 8), 0, stream>>>(Wout, woutt, 1024, 1024);
    gemm_qkv<<<dim3(16, 32), 512, 0, stream>>>(xb, wqkvt, bqkv, qws, kout, vout, kws);
    vtrans<<<dim3(32, 64), 256, 0, stream>>>(vout, vwst);
    attn_fused<<<dim3(64, 8), 256, 0, stream>>>(qws, kws, vwst, attnw);
    gemm_out<<<dim3(8, 128), 256, 0, stream>>>(attnw, woutt, bout, y);
}

// Round 4
// 299.598 us; speedup vs baseline: 1.0234x; 1.0234x over previous
//
#include <hip/hip_runtime.h>
#include <cstdint>
#include <cstddef>

typedef __bf16 bf16x8 __attribute__((ext_vector_type(8)));
typedef __bf16 bf16x4 __attribute__((ext_vector_type(4)));
typedef float  f32x4  __attribute__((ext_vector_type(4)));

#define MFMA16(a, b, c) __builtin_amdgcn_mfma_f32_16x16x32_bf16((a), (b), (c), 0, 0, 0)

// async global->LDS, 16B per lane. LDS dest MUST be wave_base + lane*16 (contiguous).
#define GLL16(gsrc, ldst)                                                              \
  __builtin_amdgcn_global_load_lds((__attribute__((address_space(1))) void*)(gsrc),    \
                                   (__attribute__((address_space(3))) void*)(ldst),    \
                                   16, 0, 0)

// q pre-scale: 1/sqrt(64) * log2(e), so attention scores land in log2 space
#define QSCALE 0.1803368801111204f

// ---------------------------------------------------------------- conversions

__global__ __launch_bounds__(256)
void cvt_f32_bf16(const float* __restrict__ in, __bf16* __restrict__ out, int n4)
{
    int i = blockIdx.x * 256 + threadIdx.x;
    if (i < n4) {
        float4 v = ((const float4*)in)[i];
        bf16x4 o;
        o[0] = (__bf16)v.x; o[1] = (__bf16)v.y; o[2] = (__bf16)v.z; o[3] = (__bf16)v.w;
        ((bf16x4*)out)[i] = o;
    }
}

// in: fp32 [K][N] row-major -> out: bf16 [N][K] row-major
__global__ __launch_bounds__(256)
void transpose_cvt(const float* __restrict__ in, __bf16* __restrict__ out, int K, int N)
{
    __shared__ __bf16 tile[32][33];
    const int n0 = blockIdx.x * 32, k0 = blockIdx.y * 32;
    const int tx = threadIdx.x, ty = threadIdx.y;
    #pragma unroll
    for (int i = 0; i < 4; ++i)
        tile[ty + i * 8][tx] = (__bf16)in[(size_t)(k0 + ty + i * 8) * N + n0 + tx];
    __syncthreads();
    #pragma unroll
    for (int i = 0; i < 4; ++i)
        out[(size_t)(n0 + ty + i * 8) * K + k0 + tx] = tile[tx][ty + i * 8];
}

// ---------------------------------------------------------------- v transpose
// vout fp32 [bh][t][64] -> vwst bf16 [bh][64][2048], with the sigma column
// permutation within each 64-block of t: position p holds t = 16*(p&3)+(p>>2),
// matching the packed P-store order (c_store = 4*lr + ni) in attn_fused.

__global__ __launch_bounds__(256)
void vtrans(const float* __restrict__ vout, __bf16* __restrict__ vwst)
{
    const int bh = blockIdx.y;
    const int t0 = blockIdx.x * 64;
    const int tid = threadIdx.x;

    __shared__ __bf16 VT[64][68];   // [d][p]

    const int tr = tid >> 4;        // t sub-row 0..15
    const int dc = (tid & 15) * 4;  // d col 0..60

    float4 vals[4];
    #pragma unroll
    for (int i = 0; i < 4; ++i)
        vals[i] = *(const float4*)&vout[((size_t)bh * 2048 + t0 + tr + 16 * i) * 64 + dc];

    // p(t_local = tr + 16*i) = 4*tr + i  -> the 4 i-values are consecutive in p
    #pragma unroll
    for (int j = 0; j < 4; ++j) {
        bf16x4 pk;
        pk[0] = (__bf16)(&vals[0].x)[j];
        pk[1] = (__bf16)(&vals[1].x)[j];
        pk[2] = (__bf16)(&vals[2].x)[j];
        pk[3] = (__bf16)(&vals[3].x)[j];
        *(bf16x4*)&VT[dc + j][4 * tr] = pk;
    }
    __syncthreads();

    #pragma unroll
    for (int k = 0; k < 2; ++k) {
        const int c = tid + 256 * k;
        const int d = c >> 3, off = (c & 7) * 8;
        bf16x8 v = *(const bf16x8*)&VT[d][off];
        *(bf16x8*)&vwst[((size_t)bh * 64 + d) * 2048 + t0 + off] = v;
    }
}

// ---------------------------------------------------------------- QKV GEMM
// 128x128 tile (round-0 structure) + T1 XCD-chunked remap. Dispatch index
// d = blockIdx.y*24 + blockIdx.x lands on XCD d%8 (round-robin). Remap so each
// XCD owns 8 contiguous m-tiles x all 24 n-tiles, n-major: the ~32 concurrent
// blocks of an XCD then touch A = 8 panels (2 MB, L2-resident) + B = 4 panels
// (1 MB) = 3 MB < 4 MB per-XCD L2. Expect FETCH_SIZE 70 -> ~45 MB.

__global__ __launch_bounds__(256)
void gemm_qkv(const __bf16* __restrict__ A, const __bf16* __restrict__ Bt,
              const float* __restrict__ bias,
              __bf16* __restrict__ qws, float* __restrict__ kout, float* __restrict__ vout,
              __bf16* __restrict__ kws)
{
    constexpr int K = 1024;
    // XCD-chunked bijective remap (1536 blocks, 1536 % 8 == 0)
    const int d   = blockIdx.y * 24 + blockIdx.x;   // HW dispatch order (x fastest)
    const int xcd = d & 7, loc = d >> 3;            // XCD = d % 8
    const int m0 = (xcd * 8 + (loc & 7)) * 128;     // 8 m-tiles per XCD, hot in L2
    const int n0 = (loc >> 3) * 128;                // n-major sweep within XCD
    const int tid = threadIdx.x;
    const int wave = tid >> 6, lane = tid & 63;
    const int quad = lane >> 4, lr = lane & 15;
    const int wrow = (wave & 1) * 64, wcol = (wave >> 1) * 64;

    __shared__ __bf16 As[128 * 32];
    __shared__ __bf16 Bs[128 * 32];

    f32x4 acc[4][4];
    #pragma unroll
    for (int mi = 0; mi < 4; ++mi)
      #pragma unroll
      for (int ni = 0; ni < 4; ++ni)
        #pragma unroll
        for (int c = 0; c < 4; ++c) acc[mi][ni][c] = 0.f;

    const int u0 = tid, u1 = tid + 256;
    const int cg0 = ((u0 & 3) ^ ((u0 >> 3) & 3)) * 8;
    const int cg1 = ((u1 & 3) ^ ((u1 >> 3) & 3)) * 8;
    const __bf16* ga0 = A  + (size_t)(m0 + (u0 >> 2)) * K + cg0;
    const __bf16* ga1 = A  + (size_t)(m0 + (u1 >> 2)) * K + cg1;
    const __bf16* gb0 = Bt + (size_t)(n0 + (u0 >> 2)) * K + cg0;
    const __bf16* gb1 = Bt + (size_t)(n0 + (u1 >> 2)) * K + cg1;
    __bf16* la0 = As + u0 * 8;
    __bf16* la1 = As + u1 * 8;
    __bf16* lb0 = Bs + u0 * 8;
    __bf16* lb1 = Bs + u1 * 8;

    const int sw = (quad ^ ((lr >> 1) & 3)) * 8;

    for (int kt = 0; kt < K; kt += 32) {
        __syncthreads();
        GLL16(ga0 + kt, la0);
        GLL16(ga1 + kt, la1);
        GLL16(gb0 + kt, lb0);
        GLL16(gb1 + kt, lb1);
        __syncthreads();
        bf16x8 af[4], bfv[4];
        #pragma unroll
        for (int mi = 0; mi < 4; ++mi)
            af[mi] = *(const bf16x8*)&As[(wrow + mi * 16 + lr) * 32 + sw];
        #pragma unroll
        for (int ni = 0; ni < 4; ++ni)
            bfv[ni] = *(const bf16x8*)&Bs[(wcol + ni * 16 + lr) * 32 + sw];
        #pragma unroll
        for (int mi = 0; mi < 4; ++mi)
          #pragma unroll
          for (int ni = 0; ni < 4; ++ni)
            acc[mi][ni] = MFMA16(af[mi], bfv[ni], acc[mi][ni]);
    }

    const int sec = n0 >> 10;  // 0=q, 1=k, 2=v (block-uniform: 128 | 1024)
    #pragma unroll
    for (int ni = 0; ni < 4; ++ni) {
        const int gn = n0 + wcol + ni * 16 + lr;
        const float bv = bias[gn];
        const int cn = gn & 1023, hh = cn >> 6, dd = cn & 63;
        #pragma unroll
        for (int mi = 0; mi < 4; ++mi) {
            const int gm0 = m0 + wrow + mi * 16 + quad * 4;
            const int b = gm0 >> 11, t0 = gm0 & 2047;
            const size_t tb = ((size_t)b * 16 + hh) * 2048;
            if (sec == 0) {
                #pragma unroll
                for (int r = 0; r < 4; ++r)
                    qws[(tb + t0 + r) * 64 + dd] = (__bf16)((acc[mi][ni][r] + bv) * QSCALE);
            } else if (sec == 1) {
                #pragma unroll
                for (int r = 0; r < 4; ++r) {
                    const float val = acc[mi][ni][r] + bv;
                    kout[(tb + t0 + r) * 64 + dd] = val;
                    kws [(tb + t0 + r) * 64 + dd] = (__bf16)val;
                }
            } else {
                #pragma unroll
                for (int r = 0; r < 4; ++r)
                    vout[(tb + t0 + r) * 64 + dd] = acc[mi][ni][r] + bv;
            }
        }
    }
}

// ---------------------------------------------------------------- out-proj GEMM
// 64x128 tile, grid (8,128) = 1024 blocks -> 4 blocks/CU for latency hiding.
// XCD affinity is already ideal by accident: dispatch d = x + 8y, d%8 = x, so
// each XCD keeps one 128-col B panel (256 KB) L2-hot and streams A once.

__global__ __launch_bounds__(256)
void gemm_out(const __bf16* __restrict__ A, const __bf16* __restrict__ Bt,
              const float* __restrict__ bias, float* __restrict__ y)
{
    constexpr int K = 1024;
    const int m0 = blockIdx.y * 64, n0 = blockIdx.x * 128;
    const int tid = threadIdx.x;
    const int wave = tid >> 6, lane = tid & 63;
    const int quad = lane >> 4, lr = lane & 15;
    const int wrow = (wave & 1) * 32, wcol = (wave >> 1) * 64;

    __shared__ __bf16 As[64 * 32];
    __shared__ __bf16 Bs[128 * 32];

    f32x4 acc[2][4];
    #pragma unroll
    for (int mi = 0; mi < 2; ++mi)
      #pragma unroll
      for (int ni = 0; ni < 4; ++ni)
        #pragma unroll
        for (int c = 0; c < 4; ++c) acc[mi][ni][c] = 0.f;

    const int ua = tid, u0 = tid, u1 = tid + 256;
    const int cga = ((ua & 3) ^ ((ua >> 3) & 3)) * 8;
    const int cg0 = ((u0 & 3) ^ ((u0 >> 3) & 3)) * 8;
    const int cg1 = ((u1 & 3) ^ ((u1 >> 3) & 3)) * 8;
    const __bf16* ga  = A  + (size_t)(m0 + (ua >> 2)) * K + cga;
    const __bf16* gb0 = Bt + (size_t)(n0 + (u0 >> 2)) * K + cg0;
    const __bf16* gb1 = Bt + (size_t)(n0 + (u1 >> 2)) * K + cg1;
    __bf16* la  = As + ua * 8;
    __bf16* lb0 = Bs + u0 * 8;
    __bf16* lb1 = Bs + u1 * 8;

    const int sw = (quad ^ ((lr >> 1) & 3)) * 8;

    for (int kt = 0; kt < K; kt += 32) {
        __syncthreads();
        GLL16(ga + kt, la);
        GLL16(gb0 + kt, lb0);
        GLL16(gb1 + kt, lb1);
        __syncthreads();
        bf16x8 af[2], bfv[4];
        #pragma unroll
        for (int mi = 0; mi < 2; ++mi)
            af[mi] = *(const bf16x8*)&As[(wrow + mi * 16 + lr) * 32 + sw];
        #pragma unroll
        for (int ni = 0; ni < 4; ++ni)
            bfv[ni] = *(const bf16x8*)&Bs[(wcol + ni * 16 + lr) * 32 + sw];
        #pragma unroll
        for (int mi = 0; mi < 2; ++mi)
          #pragma unroll
          for (int ni = 0; ni < 4; ++ni)
            acc[mi][ni] = MFMA16(af[mi], bfv[ni], acc[mi][ni]);
    }

    #pragma unroll
    for (int ni = 0; ni < 4; ++ni) {
        const int gn = n0 + wcol + ni * 16 + lr;
        const float bv = bias[gn];
        #pragma unroll
        for (int mi = 0; mi < 2; ++mi) {
            #pragma unroll
            for (int r = 0; r < 4; ++r) {
                const int gm = m0 + wrow + mi * 16 + quad * 4 + r;
                y[(size_t)gm * 1024 + gn] = acc[mi][ni][r] + bv;
            }
        }
    }
}

// ---------------------------------------------------------------- flash attention
// Grid (bh, pair): all 8 pair-blocks of a bh land on one XCD (linear id % 8 = bh % 8).
// Two serialized phases (q-tiles {x,15-x}), 34 tile-iters per block. Fixed-shift
// softmax: sacc init = -12, p = exp2(s-12), exact after final 1/l (no running max).
// 3-buffer KV, 2-deep prefetch, ONE barrier per iter (prefetch targets buf+2).

__global__ __launch_bounds__(256, 2)
void attn_fused(const __bf16* __restrict__ qws, const __bf16* __restrict__ kws,
                const __bf16* __restrict__ vwst, __bf16* __restrict__ attnws)
{
    const int bh = blockIdx.x;          // b*16 + h
    const int tid = threadIdx.x;
    const int wave = tid >> 6, lane = tid & 63;
    const int quad = lane >> 4, lr = lane & 15;

    const int jqp[2] = { (int)blockIdx.y, 15 - (int)blockIdx.y };
    const int ntp[2] = { 2 * (jqp[0] + 1), 2 * (jqp[1] + 1) };
    const int nt0 = ntp[0];
    const int ntot = 34;

    __shared__ __bf16 Ks [3][2][64][32];   // [buf][s][kv][d32]   swizzled cols
    __shared__ __bf16 Vts[3][2][64][32];   // [buf][s][d][p32]    swizzled cols
    __shared__ __bf16 Ps [4][32][72];      // per-wave P, c_store = 4*lr+ni order

    // staging addresses
    const int srow = tid >> 2;
    const int scg  = ((tid & 3) ^ ((tid >> 3) & 3)) * 8;
    const __bf16* kb = kws  + ((size_t)bh * 2048 + srow) * 64 + scg;
    const __bf16* vb = vwst + ((size_t)bh * 64 + srow) * 2048 + scg;
    char* lk = (char*)Ks  + tid * 16;   // + buf*8192 (+4096 for s1)
    char* lv = (char*)Vts + tid * 16;

    const int sw = (quad ^ ((lr >> 1) & 3)) * 8;

    bf16x8 ones;
    #pragma unroll
    for (int j = 0; j < 8; ++j) ones[j] = (__bf16)1.0f;

    // Q fragments for BOTH phases up-front (keeps vmcnt FIFO discipline clean)
    bf16x8 aq[2][2][2];
    #pragma unroll
    for (int h = 0; h < 2; ++h)
      #pragma unroll
      for (int mi = 0; mi < 2; ++mi) {
        const __bf16* qb = qws + ((size_t)bh * 2048 + jqp[h] * 128 + wave * 32 + mi * 16 + lr) * 64 + quad * 8;
        aq[h][mi][0] = *(const bf16x8*)qb;
        aq[h][mi][1] = *(const bf16x8*)(qb + 32);
      }

#define PREFETCH(j, buf)                                                \
    do {                                                                \
        GLL16(kb + (size_t)(j) * 4096,      lk + (buf) * 8192);         \
        GLL16(kb + (size_t)(j) * 4096 + 32, lk + (buf) * 8192 + 4096);  \
        GLL16(vb + (j) * 64,                lv + (buf) * 8192);         \
        GLL16(vb + (j) * 64 + 32,           lv + (buf) * 8192 + 4096);  \
    } while (0)

    // prologue: tiles 0 and 1 (phase-0 always has >= 2 tiles)
    PREFETCH(0, 0);
    PREFETCH(1, 1);

    bf16x4 oreg[2][2][4];   // [h][mi][n], r packed in vector lanes

    int pos = 0;
    for (int h = 0; h < 2; ++h) {
        const int jq = jqp[h];
        const int NT = ntp[h];

        f32x4 o_acc[2][4], l_acc[2];
        #pragma unroll
        for (int mi = 0; mi < 2; ++mi) {
            #pragma unroll
            for (int r = 0; r < 4; ++r) l_acc[mi][r] = 0.f;
            #pragma unroll
            for (int n = 0; n < 4; ++n)
                #pragma unroll
                for (int r = 0; r < 4; ++r) o_acc[mi][n][r] = 0.f;
        }

        for (int jt = 0; jt < NT; ++jt, ++pos) {
            const int cur = pos % 3;
            // tile `pos` was requested 2 iters ago; tile pos+1 is 1 deep in flight
            if (pos + 1 < ntot) {
                asm volatile("s_waitcnt vmcnt(4)" ::: "memory");
            } else {
                asm volatile("s_waitcnt vmcnt(0)" ::: "memory");
            }
            asm volatile("s_waitcnt lgkmcnt(0)" ::: "memory");
            asm volatile("s_barrier" ::: "memory");
            if (pos + 2 < ntot) {
                const int p2 = pos + 2;
                const int nj = (p2 < nt0) ? p2 : p2 - nt0;
                PREFETCH(nj, p2 % 3);
            }

            const bool lastTile = (jt == NT - 1);
            if (!(lastTile && wave < 2)) {
                // S = Q K^T, C initialized to -12 (fixed softmax shift, free)
                bf16x8 bk[4][2];
                #pragma unroll
                for (int ni = 0; ni < 4; ++ni) {
                    bk[ni][0] = *(const bf16x8*)&Ks[cur][0][ni * 16 + lr][sw];
                    bk[ni][1] = *(const bf16x8*)&Ks[cur][1][ni * 16 + lr][sw];
                }
                f32x4 sacc[2][4];
                #pragma unroll
                for (int mi = 0; mi < 2; ++mi)
                  #pragma unroll
                  for (int ni = 0; ni < 4; ++ni)
                    #pragma unroll
                    for (int c = 0; c < 4; ++c) sacc[mi][ni][c] = -12.f;
                #pragma unroll
                for (int ni = 0; ni < 4; ++ni)
                  #pragma unroll
                  for (int mi = 0; mi < 2; ++mi) {
                    sacc[mi][ni] = MFMA16(aq[h][mi][0], bk[ni][0], sacc[mi][ni]);
                    sacc[mi][ni] = MFMA16(aq[h][mi][1], bk[ni][1], sacc[mi][ni]);
                  }

                // causal mask: only waves whose rows straddle this tile
                const bool needMask = (jt == NT - 2 && wave < 2) || (lastTile && wave >= 2);
                if (needMask) {
                    const int c0 = jt * 64 + lr;
                    #pragma unroll
                    for (int mi = 0; mi < 2; ++mi) {
                        const int t0 = jq * 128 + wave * 32 + mi * 16 + quad * 4;
                        #pragma unroll
                        for (int ni = 0; ni < 4; ++ni)
                          #pragma unroll
                          for (int r = 0; r < 4; ++r)
                            if (c0 + ni * 16 > t0 + r) sacc[mi][ni][r] = -1e30f;
                    }
                }

                // p = exp2(s - 12); packed b64 store (no max, no alpha)
                #pragma unroll
                for (int mi = 0; mi < 2; ++mi)
                  #pragma unroll
                  for (int r = 0; r < 4; ++r) {
                    bf16x4 pp;
                    #pragma unroll
                    for (int ni = 0; ni < 4; ++ni)
                        pp[ni] = (__bf16)__builtin_amdgcn_exp2f(sacc[mi][ni][r]);
                    *(bf16x4*)&Ps[wave][mi * 16 + quad * 4 + r][4 * lr] = pp;
                  }

                // Ps is wave-private: drain own LDS writes, no barrier
                asm volatile("s_waitcnt lgkmcnt(0)" ::: "memory");

                // O += P V ; l += P . 1   (V rows sigma-permuted to match P)
                bf16x8 bv[4][2];
                #pragma unroll
                for (int n = 0; n < 4; ++n) {
                    bv[n][0] = *(const bf16x8*)&Vts[cur][0][n * 16 + lr][sw];
                    bv[n][1] = *(const bf16x8*)&Vts[cur][1][n * 16 + lr][sw];
                }
                #pragma unroll
                for (int mi = 0; mi < 2; ++mi) {
                    bf16x8 ap0 = *(const bf16x8*)&Ps[wave][mi * 16 + lr][quad * 8];
                    bf16x8 ap1 = *(const bf16x8*)&Ps[wave][mi * 16 + lr][32 + quad * 8];
                    l_acc[mi] = MFMA16(ap0, ones, l_acc[mi]);
                    l_acc[mi] = MFMA16(ap1, ones, l_acc[mi]);
                    #pragma unroll
                    for (int n = 0; n < 4; ++n) {
                        o_acc[mi][n] = MFMA16(ap0, bv[n][0], o_acc[mi][n]);
                        o_acc[mi][n] = MFMA16(ap1, bv[n][1], o_acc[mi][n]);
                    }
                }
            }
        }

        // normalize into registers (stores deferred to kernel end)
        #pragma unroll
        for (int mi = 0; mi < 2; ++mi)
          #pragma unroll
          for (int r = 0; r < 4; ++r) {
            const float inv = 1.f / l_acc[mi][r];
            #pragma unroll
            for (int n = 0; n < 4; ++n)
                oreg[h][mi][n][r] = (__bf16)(o_acc[mi][n][r] * inv);
          }
    }

    // epilogue: store both phases (bf16, [B,T,NH*HD] for the out-proj GEMM)
    const int b = bh >> 4, h16 = bh & 15;
    #pragma unroll
    for (int h = 0; h < 2; ++h)
      #pragma unroll
      for (int mi = 0; mi < 2; ++mi)
        #pragma unroll
        for (int r = 0; r < 4; ++r) {
            const int t = jqp[h] * 128 + wave * 32 + mi * 16 + quad * 4 + r;
            #pragma unroll
            for (int n = 0; n < 4; ++n)
                attnws[(((size_t)b * 2048 + t) * 16 + h16) * 64 + n * 16 + lr] =
                    oreg[h][mi][n][r];
        }
#undef PREFETCH
}

// ---------------------------------------------------------------- launcher

extern "C" void kernel_launch(void* const* d_in, const int* in_sizes, int n_in,
                              void* d_out, int out_size, void* d_ws, size_t ws_size,
                              hipStream_t stream)
{
    (void)in_sizes; (void)n_in; (void)out_size; (void)ws_size;

    const float* x    = (const float*)d_in[0];
    const float* Wqkv = (const float*)d_in[1];
    const float* bqkv = (const float*)d_in[2];
    const float* Wout = (const float*)d_in[3];
    const float* bout = (const float*)d_in[4];

    float* y    = (float*)d_out;          // [4,2048,1024]
    float* kout = y + 8388608;            // [4,16,2048,64]
    float* vout = kout + 8388608;         // [4,16,2048,64]

    char* ws = (char*)d_ws;
    __bf16* xb    = (__bf16*)(ws);                       // 16 MB  [8192,1024]
    __bf16* wqkvt = (__bf16*)(ws + (16u << 20));         //  6 MB  [3072,1024]
    __bf16* woutt = (__bf16*)(ws + (22u << 20));         //  2 MB  [1024,1024]
    __bf16* qws   = (__bf16*)(ws + (24u << 20));         // 16 MB  [64,2048,64]  (pre-scaled)
    __bf16* kws   = (__bf16*)(ws + (40u << 20));         // 16 MB  [64,2048,64]
    __bf16* vwst  = (__bf16*)(ws + (56u << 20));         // 16 MB  [64,64,2048]  (sigma-permuted)
    __bf16* attnw = (__bf16*)(ws + (72u << 20));         // 16 MB  [8192,1024]

    cvt_f32_bf16<<<8192, 256, 0, stream>>>(x, xb, 2097152);
    transpose_cvt<<<dim3(96, 32), dim3(32, 8), 0, stream>>>(Wqkv, wqkvt, 1024, 3072);
    transpose_cvt<<<dim3(32, 32), dim3(32, 8), 0, stream>>>(Wout, woutt, 1024, 1024);
    gemm_qkv<<<dim3(24, 64), 256, 0, stream>>>(xb, wqkvt, bqkv, qws, kout, vout, kws);
    vtrans<<<dim3(32, 64), 256, 0, stream>>>(vout, vwst);
    attn_fused<<<dim3(64, 8), 256, 0, stream>>>(qws, kws, vwst, attnw);
    gemm_out<<<dim3(8, 128), 256, 0, stream>>>(attnw, woutt, bout, y);
}